// Round 17
// baseline (67.266 us; speedup 1.0000x reference)
//
#include <hip/hip_runtime.h>
#include <cstdint>
#include <cstddef>

#define NTOT   22743     // 1083 + 4332 + 17328
#define N1     1083
#define N12    5415
#define BATCH  64
#define KCAND  512
#define NSEG   16        // segments per image
#define SEGLEN 1422      // ceil(NTOT/NSEG)
#define CAPS   384       // per-(b,c,seg) capacity (expected ~114)
#define CAP    4096      // per-(b,c) total candidate capacity (4 regs/thread)
#define MAXPC  100
#define MAXTOT 100
#define KITER  6         // ceil(SEGLEN/256)

__device__ __forceinline__ float sigmoidf(float x) { return 1.0f / (1.0f + expf(-x)); }
__device__ __forceinline__ int SK4(int j) { return j + ((j >> 6) << 2); }  // float4-friendly skew

// ---------------------------------------------------------------- kernel 1
// filter+decode: block = (image b, segment s). Phase A: 6 independent float4
// row loads (q[3..6]) -> registers. Phase B: scores + ballot-aggregated LDS
// append; pred lanes ALSO decode the box here (rows are L1-hot) and stash it.
// Writes packed candKV (u64) + candBox (float4) to PRIVATE global slots.
__global__ __launch_bounds__(256) void score_filter_kernel(
    const float* __restrict__ p1, const float* __restrict__ p2,
    const float* __restrict__ p3, const float* __restrict__ anch,
    unsigned long long* __restrict__ candKV, float4* __restrict__ candBox,
    uint32_t* __restrict__ counts)
{
  const int blk  = blockIdx.x;
  const int b    = blk >> 4;
  const int s    = blk & 15;
  const int tid  = threadIdx.x;
  const int lane = tid & 63;

  __shared__ unsigned long long lkv[2][CAPS];   // 6 KB
  __shared__ float4             lbox[2][CAPS];  // 12 KB
  __shared__ uint32_t           lcnt[2];

  if (tid < 2) lcnt[tid] = 0u;
  __syncthreads();

  const int beg = s * SEGLEN;
  const int end = (beg + SEGLEN < NTOT) ? beg + SEGLEN : NTOT;

  // ---- phase A: issue all row loads (independent -> deep MLP)
  float4 v[KITER];
  #pragma unroll
  for (int k = 0; k < KITER; ++k) {
    int i0 = beg + tid + k * 256;
    if (i0 < end) {
      const float* p; int local, per;
      if (i0 < N1)       { p = p1; local = i0;        per = 1083; }
      else if (i0 < N12) { p = p2; local = i0 - N1;   per = 4332; }
      else               { p = p3; local = i0 - N12;  per = 17328; }
      const float* q = p + ((size_t)b * per + local) * 7;
      v[k] = *(const float4*)(q + 3);          // (q3, q4, q5, q6) — in-bounds
    } else {
      v[k] = make_float4(0.f, -1.f, 0.f, 0.f); // q4 = -1 -> inactive
    }
  }

  // ---- phase B: scores + appends (+ box decode for pred lanes)
  #pragma unroll
  for (int k = 0; k < KITER; ++k) {
    int i0 = beg + tid + k * 256;
    float s0 = 0.f, s1 = 0.f;
    float q4 = v[k].y;
    if (q4 > 0.f) {                 // sig(q4)<=0.5 -> product < 0.5 strictly
      float obj = sigmoidf(q4);
      s0 = obj * sigmoidf(v[k].z);
      s1 = obj * sigmoidf(v[k].w);
    }
    #pragma unroll
    for (int c = 0; c < 2; c++) {
      float sc = (c == 0) ? s0 : s1;
      bool pred = sc > 0.5f;
      unsigned long long m = __ballot(pred ? 1 : 0);
      if (m != 0ull) {
        int leader = (int)__ffsll(m) - 1;
        uint32_t base = 0u;
        if (lane == leader) base = atomicAdd(&lcnt[c], (uint32_t)__popcll(m));
        base = (uint32_t)__shfl((int)base, leader);
        if (pred) {
          uint32_t off = base + (uint32_t)__popcll(m & ((1ull << lane) - 1ull));
          if (off < CAPS) {
            lkv[c][off] = ((unsigned long long)__float_as_uint(sc) << 32)
                          | (uint32_t)(~(uint32_t)i0);
            // decode box here — row lines are L1-hot from phase A's stream
            const float* p; int local, per, g, abase;
            if (i0 < N1)       { p = p1; local = i0;        per = 1083;  g = 19; abase = 6; }
            else if (i0 < N12) { p = p2; local = i0 - N1;   per = 4332;  g = 38; abase = 3; }
            else               { p = p3; local = i0 - N12;  per = 17328; g = 76; abase = 0; }
            const float* q = p + ((size_t)b * per + local) * 7;
            float q0 = q[0], q1v = q[1], q2v = q[2];
            float q3v = v[k].x;
            int a    = local % 3;
            int cell = local / 3;
            int col  = cell % g;
            int row  = cell / g;
            float aw = anch[(abase + a) * 2 + 0];
            float ah = anch[(abase + a) * 2 + 1];
            float x = (sigmoidf(q0)  + (float)col) / (float)g;
            float y = (sigmoidf(q1v) + (float)row) / (float)g;
            float w = expf(q2v) * aw;
            float h = expf(q3v) * ah;
            float x1 = x - w * 0.5f;
            float y1 = y - h * 0.5f;
            lbox[c][off] = make_float4(x1, y1, x1 + w, y1 + h);
          }
        }
      }
    }
  }
  __syncthreads();

  #pragma unroll
  for (int c = 0; c < 2; c++) {
    uint32_t cnt = lcnt[c]; if (cnt > CAPS) cnt = CAPS;
    unsigned long long* dk = candKV  + (size_t)((b * 2 + c) * NSEG + s) * CAPS;
    float4*             db = candBox + (size_t)((b * 2 + c) * NSEG + s) * CAPS;
    for (uint32_t i = tid; i < cnt; i += 256) { dk[i] = lkv[c][i]; db[i] = lbox[c][i]; }
    if (tid == 0) counts[(b * 2 + c) * NSEG + s] = cnt;
  }
}

// ---------------------------------------------------------------- kernel 2
// one block (1024 thr) per (image, class). Register candidates (4 packed
// u64/thread from candKV). DIRECT bucket-rank top-512; box fetch for
// rank<512 from L2-hot candBox (no raw-tensor gathers at all). Then
// broadcast-float4 mask NMS + 16-deep prefetched serial bitmask pass.
__global__ __launch_bounds__(1024) void nms_kernel(
    const unsigned long long* __restrict__ candKV,
    const float4* __restrict__ candBox, const uint32_t* __restrict__ counts,
    float* __restrict__ selScore, float* __restrict__ selBox,
    int* __restrict__ selRank, int* __restrict__ selCount)
{
  const int bc   = blockIdx.x;   // b*2 + c
  const int tid  = threadIdx.x;
  const int lane = tid & 63;

  __shared__ __attribute__((aligned(16))) unsigned long long bord[CAP];  // 32 KB
  __shared__ __attribute__((aligned(16))) float bx1[544];
  __shared__ __attribute__((aligned(16))) float by1[544];
  __shared__ __attribute__((aligned(16))) float bx2[544];
  __shared__ __attribute__((aligned(16))) float by2[544];
  __shared__ __attribute__((aligned(16))) float ar[544];                 // 10.6 KB
  __shared__ uint32_t           skey[512];      // 2 KB
  __shared__ unsigned long long msk[128][9];    // 9 KB (row stride 9 = skew)
  __shared__ unsigned long long kword[8];
  __shared__ uint32_t           hist3[768];     // 3 KB: bcnt / boff / bpre
  __shared__ uint32_t           svar[8];

  // ---- init LDS
  if (tid < 768) hist3[tid] = 0u;
  if (tid == 0) svar[5] = 0u;
  if (tid < 512) {
    skey[tid] = 0u; int p = SK4(tid);
    bx1[p] = 0.f; by1[p] = 0.f; bx2[p] = 0.f; by2[p] = 0.f; ar[p] = 0.f;
  }

  // ---- uniform prefix of segment counts (scalar global loads)
  uint32_t pc[17];
  pc[0] = 0;
  #pragma unroll
  for (int t = 0; t < 16; ++t) {
    uint32_t c = counts[bc * NSEG + t];
    if (c > CAPS) c = CAPS;
    pc[t + 1] = pc[t] + c;
  }
  const int n = ((int)pc[16] < CAP) ? (int)pc[16] : CAP;
  const int limit = (n < KCAND) ? n : KCAND;

  // ---- load my candidates into registers (packed u64) + remember flat pos
  int pos0 = -1, pos1 = -1, pos2 = -1, pos3 = -1;
  auto loadc = [&](int i, int& pos) -> unsigned long long {
    if (i >= n) { pos = -1; return 0ull; }
    uint32_t ps = 0; int s = 0;
    #pragma unroll
    for (int t = 1; t < 16; ++t) {
      bool ge = (uint32_t)i >= pc[t];
      s += (int)ge; ps = ge ? pc[t] : ps;
    }
    pos = (int)((size_t)(bc * NSEG + s) * CAPS + (i - (int)ps));
    return candKV[pos];
  };
  unsigned long long v0 = loadc(tid, pos0);
  unsigned long long v1 = loadc(tid + 1024, pos1);
  unsigned long long v2 = loadc(tid + 2048, pos2);
  unsigned long long v3 = loadc(tid + 3072, pos3);
  __syncthreads();

  uint32_t* bcnt = hist3;
  uint32_t* boff = hist3 + 256;
  uint32_t* bpre = hist3 + 512;

  // ---- bucket counts (bucket = key bits [22:15] = packed bits [54:47])
  #define BKT(vv) ((uint32_t)(((vv) >> 47) & 255u))
  if (v0) atomicAdd(&bcnt[BKT(v0)], 1u);
  if (v1) atomicAdd(&bcnt[BKT(v1)], 1u);
  if (v2) atomicAdd(&bcnt[BKT(v2)], 1u);
  if (v3) atomicAdd(&bcnt[BKT(v3)], 1u);
  __syncthreads();

  // ---- suffix-exclusive bucket prefix (count in strictly-greater buckets)
  if (tid < 64) {
    uint32_t h0 = bcnt[lane * 4 + 0], h1 = bcnt[lane * 4 + 1];
    uint32_t h2 = bcnt[lane * 4 + 2], h3 = bcnt[lane * 4 + 3];
    uint32_t s3 = h3, s2 = h2 + s3, s1 = h1 + s2, s0 = h0 + s1;
    uint32_t acc = s0;
    #pragma unroll
    for (int o = 1; o < 64; o <<= 1) {
      uint32_t vv = __shfl_down(acc, (unsigned)o);
      acc += (lane + o < 64) ? vv : 0u;
    }
    uint32_t above = acc - s0;              // count in quads above this one
    bpre[lane * 4 + 0] = above + s1;
    bpre[lane * 4 + 1] = above + s2;
    bpre[lane * 4 + 2] = above + s3;
    bpre[lane * 4 + 3] = above;
  }
  __syncthreads();

  // ---- scatter bucket-major
  if (v0) bord[bpre[BKT(v0)] + atomicAdd(&boff[BKT(v0)], 1u)] = v0;
  if (v1) bord[bpre[BKT(v1)] + atomicAdd(&boff[BKT(v1)], 1u)] = v1;
  if (v2) bord[bpre[BKT(v2)] + atomicAdd(&boff[BKT(v2)], 1u)] = v2;
  if (v3) bord[bpre[BKT(v3)] + atomicAdd(&boff[BKT(v3)], 1u)] = v3;
  __syncthreads();

  // ---- exact rank + L2-hot box fetch for rank < 512
  auto rankdec = [&](unsigned long long e, int pos) {
    if (e == 0ull) return;
    const uint32_t B = BKT(e);
    const uint32_t lo = bpre[B], sz = bcnt[B];
    if ((int)lo < KCAND) {
      int rank = (int)lo;
      for (uint32_t j = lo; j < lo + sz; ++j) rank += (int)(bord[j] > e);
      if (rank < KCAND) {
        float4 bb = candBox[pos];             // L2-hot (sf just wrote it)
        int p = SK4(rank);
        bx1[p] = bb.x; by1[p] = bb.y; bx2[p] = bb.z; by2[p] = bb.w;
        ar[p]  = fmaxf(bb.z - bb.x, 0.f) * fmaxf(bb.w - bb.y, 0.f);
        skey[rank] = (uint32_t)(e >> 32);
      }
    }
  };
  rankdec(v0, pos0); rankdec(v1, pos1); rankdec(v2, pos2); rankdec(v3, pos3);
  #undef BKT
  __syncthreads();

  // ---- chunked NMS: broadcast-float4 mask words + serial bitmask pass
  unsigned long long Kw = 0ull;   // kept bitmap: wave-0 lane l (<8) owns word l
  int kept = 0;
  const int r = tid & 127;        // row within chunk
  const int w = tid >> 7;         // mask word (wave-uniform)

  for (int ch = 0; ch < 4; ++ch) {
    const int base = ch * 128;
    int rows = limit - base; if (rows > 128) rows = 128;

    if (r < rows) {
      const int i = base + r;
      if (w <= (i >> 6)) {
        const int ip = SK4(i);
        const float x1i = bx1[ip], y1i = by1[ip], x2i = bx2[ip], y2i = by2[ip];
        const float ai = ar[ip];
        unsigned long long mrow = 0ull;
        #pragma unroll
        for (int m4 = 0; m4 < 16; ++m4) {
          const int j0 = (w << 6) + (m4 << 2);
          const int a  = j0 + (w << 2);          // SK4(j0), j0>>6 == w
          float4 X1 = *(const float4*)&bx1[a];
          float4 Y1 = *(const float4*)&by1[a];
          float4 X2 = *(const float4*)&bx2[a];
          float4 Y2 = *(const float4*)&by2[a];
          float4 AR = *(const float4*)&ar[a];
          #define IOU_BIT(JX1,JY1,JX2,JY2,JAR,J)                              \
            { float iw = fminf(x2i,(JX2)) - fmaxf(x1i,(JX1));                 \
              float ih = fminf(y2i,(JY2)) - fmaxf(y1i,(JY1));                 \
              iw = fmaxf(iw,0.f); ih = fmaxf(ih,0.f);                        \
              float inter = iw*ih;                                            \
              float uni = fmaxf(ai + (JAR) - inter, 1e-9f);                   \
              if ((inter/uni > 0.5f) && ((J) < i))                            \
                mrow |= 1ull << ((J) & 63); }
          IOU_BIT(X1.x, Y1.x, X2.x, Y2.x, AR.x, j0 + 0)
          IOU_BIT(X1.y, Y1.y, X2.y, Y2.y, AR.y, j0 + 1)
          IOU_BIT(X1.z, Y1.z, X2.z, Y2.z, AR.z, j0 + 2)
          IOU_BIT(X1.w, Y1.w, X2.w, Y2.w, AR.w, j0 + 3)
          #undef IOU_BIT
        }
        msk[r][w] = mrow;
      } else {
        msk[r][w] = 0ull;
      }
    }
    __syncthreads();

    if (tid < 64) {
      bool stop = false;
      for (int g = 0; g < 8 && !stop; ++g) {     // 16-deep prefetch groups
        int r0 = g * 16;
        if (r0 >= rows) break;
        unsigned long long wbuf[16];
        #pragma unroll
        for (int k2 = 0; k2 < 16; ++k2)
          wbuf[k2] = (lane < 8 && (r0 + k2) < rows) ? msk[r0 + k2][lane] : 0ull;
        #pragma unroll
        for (int k2 = 0; k2 < 16; ++k2) {
          if (!stop) {
            int rr = r0 + k2;
            if (rr >= rows) { stop = true; }
            else {
              int i = base + rr;
              bool ov = (Kw & wbuf[k2]) != 0ull;
              if (!__any(ov)) {
                if (lane == (i >> 6)) Kw |= 1ull << (i & 63);
                if (++kept >= MAXPC) stop = true;
              }
            }
          }
        }
      }
      if (lane == 0) svar[5] = (kept >= MAXPC || (base + (rows > 0 ? rows : 0)) >= limit) ? 1u : 0u;
    }
    __syncthreads();
    if (svar[5] != 0u) break;     // block-uniform break
  }

  if (tid < 8) kword[tid] = Kw;   // wave-0 lanes 0..7 hold the kept words
  __syncthreads();

  // ---- write kept entries (prefix over kword)
  if (tid < 512) {
    int rr = tid;
    int wr = rr >> 6;
    unsigned long long kw = kword[wr];
    if ((kw >> (rr & 63)) & 1ull) {
      uint32_t p = 0;
      for (int ww = 0; ww < wr; ++ww) p += (uint32_t)__popcll(kword[ww]);
      p += (uint32_t)__popcll(kw & ((1ull << (rr & 63)) - 1ull));
      selScore[bc * MAXPC + p] = __uint_as_float(skey[rr]);
      selRank[bc * MAXPC + p]  = rr;
      int rp = SK4(rr);
      float* o = &selBox[(size_t)(bc * MAXPC + p) * 4];
      o[0] = bx1[rp]; o[1] = by1[rp]; o[2] = bx2[rp]; o[3] = by2[rp];
    }
  }
  if (tid == 0) {
    uint32_t tot = 0;
    for (int ww = 0; ww < 8; ++ww) tot += (uint32_t)__popcll(kword[ww]);
    selCount[bc] = (int)tot;
  }
}

// ---------------------------------------------------------------- kernel 3
// per image: merge the two class lists (<=200), exact top-100 by
// (score desc, flat index asc) via rank-by-count, write outputs. (R13-identical)
__global__ __launch_bounds__(256) void merge_kernel(
    const float* __restrict__ selScore, const float* __restrict__ selBox,
    const int* __restrict__ selRank, const int* __restrict__ selCount,
    float* __restrict__ out)
{
  const int b   = blockIdx.x;
  const int tid = threadIdx.x;
  __shared__ float    es[200];
  __shared__ uint32_t ek[200];
  __shared__ float    eb[200][4];
  const int c0  = selCount[b * 2 + 0];
  const int c1  = selCount[b * 2 + 1];
  const int tot = c0 + c1;                      // <= 200

  if (tid < tot) {
    int cls  = (tid < c0) ? 0 : 1;
    int slot = (cls == 0) ? tid : (tid - c0);
    int src  = (b * 2 + cls) * MAXPC + slot;
    es[tid] = selScore[src];
    ek[tid] = (uint32_t)(cls * KCAND + selRank[src]);   // flat index in (2,512)
    eb[tid][0] = selBox[(size_t)src * 4 + 0];
    eb[tid][1] = selBox[(size_t)src * 4 + 1];
    eb[tid][2] = selBox[(size_t)src * 4 + 2];
    eb[tid][3] = selBox[(size_t)src * 4 + 3];
  }
  __syncthreads();

  float* outBoxes  = out;
  float* outScores = out + (size_t)BATCH * MAXTOT * 4;
  float* outCls    = outScores + (size_t)BATCH * MAXTOT;
  float* outCnt    = outCls + (size_t)BATCH * MAXTOT;
  const int filled = (tot < MAXTOT) ? tot : MAXTOT;

  if (tid < tot) {
    float    s  = es[tid];
    uint32_t fk = ek[tid];
    int rank = 0;
    for (int j = 0; j < tot; j++)
      rank += (int)((es[j] > s) || (es[j] == s && ek[j] < fk));
    if (rank < MAXTOT) {                       // kept: s > 0.5 > 0 always
      outScores[b * MAXTOT + rank] = s;
      outCls[b * MAXTOT + rank]    = (float)(fk >> 9);
      float* ob = &outBoxes[(size_t)(b * MAXTOT + rank) * 4];
      ob[0] = fminf(fmaxf(eb[tid][0], 0.f), 1.f);
      ob[1] = fminf(fmaxf(eb[tid][1], 0.f), 1.f);
      ob[2] = fminf(fmaxf(eb[tid][2], 0.f), 1.f);
      ob[3] = fminf(fmaxf(eb[tid][3], 0.f), 1.f);
    }
  }
  if (tid >= filled && tid < MAXTOT) {         // zero-fill unused slots
    outScores[b * MAXTOT + tid] = 0.f;
    outCls[b * MAXTOT + tid]    = 0.f;
    float* ob = &outBoxes[(size_t)(b * MAXTOT + tid) * 4];
    ob[0] = 0.f; ob[1] = 0.f; ob[2] = 0.f; ob[3] = 0.f;
  }
  if (tid == 0) outCnt[b] = (float)filled;
}

// ---------------------------------------------------------------- launch
extern "C" void kernel_launch(void* const* d_in, const int* in_sizes, int n_in,
                              void* d_out, int out_size, void* d_ws, size_t ws_size,
                              hipStream_t stream)
{
  const float* p1   = (const float*)d_in[0];
  const float* p2   = (const float*)d_in[1];
  const float* p3   = (const float*)d_in[2];
  const float* anch = (const float*)d_in[3];

  uint8_t* ws = (uint8_t*)d_ws;
  uint32_t*           counts  = (uint32_t*)ws;                       // 2048 u32
  unsigned long long* candKV  = (unsigned long long*)(ws + 16384);   // 6 MB
  float4*             candBox = (float4*)(ws + 16384 + (size_t)128 * NSEG * CAPS * 8); // 12 MB
  uint8_t* wp = ws + 16384 + (size_t)128 * NSEG * CAPS * 8 + (size_t)128 * NSEG * CAPS * 16;
  float*    selScore = (float*)wp;         wp += (size_t)BATCH * 2 * MAXPC * 4;
  float*    selBox   = (float*)wp;         wp += (size_t)BATCH * 2 * MAXPC * 16;
  int*      selRank  = (int*)wp;           wp += (size_t)BATCH * 2 * MAXPC * 4;
  int*      selCount = (int*)wp;

  score_filter_kernel<<<BATCH * NSEG, 256, 0, stream>>>(p1, p2, p3, anch,
                                                        candKV, candBox, counts);
  nms_kernel<<<BATCH * 2, 1024, 0, stream>>>(candKV, candBox, counts,
                                             selScore, selBox, selRank, selCount);
  merge_kernel<<<BATCH, 256, 0, stream>>>(selScore, selBox, selRank, selCount,
                                          (float*)d_out);
}

// Round 18
// 56.686 us; speedup vs baseline: 1.1866x; 1.1866x over previous
//
#include <hip/hip_runtime.h>
#include <cstdint>
#include <cstddef>

#define NTOT   22743     // 1083 + 4332 + 17328
#define N1     1083
#define N12    5415
#define BATCH  64
#define KCAND  512
#define NSEG   16        // segments per image
#define SEGLEN 1422      // ceil(NTOT/NSEG)
#define CAPS   384       // per-(b,c,seg) capacity (expected ~114)
#define CAP    4096      // per-(b,c) total candidate capacity (4 regs/thread)
#define MAXPC  100
#define MAXTOT 100
#define KITER  6         // ceil(SEGLEN/256)

__device__ __forceinline__ float sigmoidf(float x) { return 1.0f / (1.0f + expf(-x)); }
__device__ __forceinline__ int SK4(int j) { return j + ((j >> 6) << 2); }  // float4-friendly skew

// ---------------------------------------------------------------- kernel 1
// filter: block = (image b, segment s). Phase A: 6 independent float4 row
// loads (q[3..6]) -> registers. Phase B: scores + ballot-aggregated LDS
// append. PRIVATE global slot; no global atomics. (R13 best-known)
__global__ __launch_bounds__(256) void score_filter_kernel(
    const float* __restrict__ p1, const float* __restrict__ p2,
    const float* __restrict__ p3, uint2* __restrict__ cand,
    uint32_t* __restrict__ counts)
{
  const int blk  = blockIdx.x;
  const int b    = blk >> 4;
  const int s    = blk & 15;
  const int tid  = threadIdx.x;
  const int lane = tid & 63;

  __shared__ uint2    lst[2][CAPS];
  __shared__ uint32_t lcnt[2];

  if (tid < 2) lcnt[tid] = 0u;
  __syncthreads();

  const int beg = s * SEGLEN;
  const int end = (beg + SEGLEN < NTOT) ? beg + SEGLEN : NTOT;

  float4 v[KITER];
  #pragma unroll
  for (int k = 0; k < KITER; ++k) {
    int i0 = beg + tid + k * 256;
    if (i0 < end) {
      const float* p; int local, per;
      if (i0 < N1)       { p = p1; local = i0;        per = 1083; }
      else if (i0 < N12) { p = p2; local = i0 - N1;   per = 4332; }
      else               { p = p3; local = i0 - N12;  per = 17328; }
      const float* q = p + ((size_t)b * per + local) * 7;
      v[k] = *(const float4*)(q + 3);          // (q3, q4, q5, q6) — in-bounds
    } else {
      v[k] = make_float4(0.f, -1.f, 0.f, 0.f); // q4 = -1 -> inactive
    }
  }

  #pragma unroll
  for (int k = 0; k < KITER; ++k) {
    int i0 = beg + tid + k * 256;
    float s0 = 0.f, s1 = 0.f;
    float q4 = v[k].y;
    if (q4 > 0.f) {                 // sig(q4)<=0.5 -> product < 0.5 strictly
      float obj = sigmoidf(q4);
      s0 = obj * sigmoidf(v[k].z);
      s1 = obj * sigmoidf(v[k].w);
    }
    #pragma unroll
    for (int c = 0; c < 2; c++) {
      float sc = (c == 0) ? s0 : s1;
      bool pred = sc > 0.5f;
      unsigned long long m = __ballot(pred ? 1 : 0);
      if (m != 0ull) {
        int leader = (int)__ffsll(m) - 1;
        uint32_t base = 0u;
        if (lane == leader) base = atomicAdd(&lcnt[c], (uint32_t)__popcll(m));
        base = (uint32_t)__shfl((int)base, leader);
        if (pred) {
          uint32_t off = base + (uint32_t)__popcll(m & ((1ull << lane) - 1ull));
          if (off < CAPS) lst[c][off] = make_uint2(__float_as_uint(sc), (uint32_t)i0);
        }
      }
    }
  }
  __syncthreads();

  #pragma unroll
  for (int c = 0; c < 2; c++) {
    uint32_t cnt = lcnt[c]; if (cnt > CAPS) cnt = CAPS;
    uint2* dst = cand + ((size_t)((b * 2 + c) * NSEG + s)) * CAPS;
    for (uint32_t i = tid; i < cnt; i += 256) dst[i] = lst[c][i];
    if (tid == 0) counts[(b * 2 + c) * NSEG + s] = cnt;
  }
}

// box decode for global candidate index i of image b
__device__ void decode_box(const float* __restrict__ p1, const float* __restrict__ p2,
                           const float* __restrict__ p3, const float* __restrict__ anch,
                           int b, int i, float bb[4])
{
  const float* p; int local, g, abase, per;
  if (i < N1)       { p = p1; local = i;       g = 19; abase = 6; per = 1083; }
  else if (i < N12) { p = p2; local = i - N1;  g = 38; abase = 3; per = 4332; }
  else              { p = p3; local = i - N12; g = 76; abase = 0; per = 17328; }
  const float* q = p + ((size_t)b * per + local) * 7;
  int a    = local % 3;
  int cell = local / 3;
  int col  = cell % g;
  int row  = cell / g;
  float aw = anch[(abase + a) * 2 + 0];
  float ah = anch[(abase + a) * 2 + 1];
  float x = (sigmoidf(q[0]) + (float)col) / (float)g;
  float y = (sigmoidf(q[1]) + (float)row) / (float)g;
  float w = expf(q[2]) * aw;
  float h = expf(q[3]) * ah;
  float x1 = x - w * 0.5f;
  float y1 = y - h * 0.5f;
  bb[0] = x1; bb[1] = y1; bb[2] = x1 + w; bb[3] = y1 + h;
}

// ---------------------------------------------------------------- kernel 2
// one block (1024 thr) per (image, class). Register candidates (4 packed
// u64/thread). DIRECT bucket-rank top-512, lazy decode, broadcast-float4
// mask NMS + 8-deep serial bitmask pass. (R13 best-known)
__global__ __launch_bounds__(1024) void nms_kernel(
    const uint2* __restrict__ cand, const uint32_t* __restrict__ counts,
    const float* __restrict__ p1, const float* __restrict__ p2,
    const float* __restrict__ p3, const float* __restrict__ anch,
    float* __restrict__ selScore, float* __restrict__ selBox,
    int* __restrict__ selRank, int* __restrict__ selCount)
{
  const int bc   = blockIdx.x;   // b*2 + c
  const int b    = bc >> 1;
  const int tid  = threadIdx.x;
  const int lane = tid & 63;

  __shared__ __attribute__((aligned(16))) unsigned long long bord[CAP];  // 32 KB
  __shared__ __attribute__((aligned(16))) float bx1[544];
  __shared__ __attribute__((aligned(16))) float by1[544];
  __shared__ __attribute__((aligned(16))) float bx2[544];
  __shared__ __attribute__((aligned(16))) float by2[544];
  __shared__ __attribute__((aligned(16))) float ar[544];                 // 10.6 KB
  __shared__ uint32_t           skey[512];      // 2 KB
  __shared__ unsigned long long msk[128][9];    // 9 KB (row stride 9 = skew)
  __shared__ unsigned long long kword[8];
  __shared__ uint32_t           hist3[768];     // 3 KB: bcnt / boff / bpre
  __shared__ uint32_t           svar[8];

  // ---- init LDS
  if (tid < 768) hist3[tid] = 0u;
  if (tid == 0) svar[5] = 0u;
  if (tid < 512) {
    skey[tid] = 0u; int p = SK4(tid);
    bx1[p] = 0.f; by1[p] = 0.f; bx2[p] = 0.f; by2[p] = 0.f; ar[p] = 0.f;
  }

  // ---- uniform prefix of segment counts (scalar global loads)
  uint32_t pc[17];
  pc[0] = 0;
  #pragma unroll
  for (int t = 0; t < 16; ++t) {
    uint32_t c = counts[bc * NSEG + t];
    if (c > CAPS) c = CAPS;
    pc[t + 1] = pc[t] + c;
  }
  const int n = ((int)pc[16] < CAP) ? (int)pc[16] : CAP;
  const int limit = (n < KCAND) ? n : KCAND;

  // ---- load my candidates into registers (packed: key<<32 | ~idx)
  unsigned long long v0, v1, v2, v3;
  auto loadc = [&](int i) -> unsigned long long {
    if (i >= n) return 0ull;
    uint32_t ps = 0; int s = 0;
    #pragma unroll
    for (int t = 1; t < 16; ++t) {
      bool ge = (uint32_t)i >= pc[t];
      s += (int)ge; ps = ge ? pc[t] : ps;
    }
    uint2 e = cand[(size_t)(bc * NSEG + s) * CAPS + (i - (int)ps)];
    return ((unsigned long long)e.x << 32) | (uint32_t)(~e.y);
  };
  v0 = loadc(tid); v1 = loadc(tid + 1024); v2 = loadc(tid + 2048); v3 = loadc(tid + 3072);
  __syncthreads();

  uint32_t* bcnt = hist3;
  uint32_t* boff = hist3 + 256;
  uint32_t* bpre = hist3 + 512;

  // ---- bucket counts (bucket = key bits [22:15] = packed bits [54:47])
  #define BKT(vv) ((uint32_t)(((vv) >> 47) & 255u))
  if (v0) atomicAdd(&bcnt[BKT(v0)], 1u);
  if (v1) atomicAdd(&bcnt[BKT(v1)], 1u);
  if (v2) atomicAdd(&bcnt[BKT(v2)], 1u);
  if (v3) atomicAdd(&bcnt[BKT(v3)], 1u);
  __syncthreads();

  // ---- suffix-exclusive bucket prefix (count in strictly-greater buckets)
  if (tid < 64) {
    uint32_t h0 = bcnt[lane * 4 + 0], h1 = bcnt[lane * 4 + 1];
    uint32_t h2 = bcnt[lane * 4 + 2], h3 = bcnt[lane * 4 + 3];
    uint32_t s3 = h3, s2 = h2 + s3, s1 = h1 + s2, s0 = h0 + s1;
    uint32_t acc = s0;
    #pragma unroll
    for (int o = 1; o < 64; o <<= 1) {
      uint32_t vv = __shfl_down(acc, (unsigned)o);
      acc += (lane + o < 64) ? vv : 0u;
    }
    uint32_t above = acc - s0;              // count in quads above this one
    bpre[lane * 4 + 0] = above + s1;
    bpre[lane * 4 + 1] = above + s2;
    bpre[lane * 4 + 2] = above + s3;
    bpre[lane * 4 + 3] = above;
  }
  __syncthreads();

  // ---- scatter bucket-major
  if (v0) bord[bpre[BKT(v0)] + atomicAdd(&boff[BKT(v0)], 1u)] = v0;
  if (v1) bord[bpre[BKT(v1)] + atomicAdd(&boff[BKT(v1)], 1u)] = v1;
  if (v2) bord[bpre[BKT(v2)] + atomicAdd(&boff[BKT(v2)], 1u)] = v2;
  if (v3) bord[bpre[BKT(v3)] + atomicAdd(&boff[BKT(v3)], 1u)] = v3;
  __syncthreads();

  // ---- exact rank + decode for rank < 512 (lazy decode)
  auto rankdec = [&](unsigned long long e) {
    if (e == 0ull) return;
    const uint32_t B = BKT(e);
    const uint32_t lo = bpre[B], sz = bcnt[B];
    if ((int)lo < KCAND) {
      int rank = (int)lo;
      for (uint32_t j = lo; j < lo + sz; ++j) rank += (int)(bord[j] > e);
      if (rank < KCAND) {
        int idx = (int)(~(uint32_t)e);
        float bb[4];
        decode_box(p1, p2, p3, anch, b, idx, bb);
        int p = SK4(rank);
        bx1[p] = bb[0]; by1[p] = bb[1]; bx2[p] = bb[2]; by2[p] = bb[3];
        ar[p]  = fmaxf(bb[2] - bb[0], 0.f) * fmaxf(bb[3] - bb[1], 0.f);
        skey[rank] = (uint32_t)(e >> 32);
      }
    }
  };
  rankdec(v0); rankdec(v1); rankdec(v2); rankdec(v3);
  #undef BKT
  __syncthreads();

  // ---- chunked NMS: broadcast-float4 mask words + serial bitmask pass
  unsigned long long Kw = 0ull;   // kept bitmap: wave-0 lane l (<8) owns word l
  int kept = 0;
  const int r = tid & 127;        // row within chunk
  const int w = tid >> 7;         // mask word (wave-uniform)

  for (int ch = 0; ch < 4; ++ch) {
    const int base = ch * 128;
    int rows = limit - base; if (rows > 128) rows = 128;

    if (r < rows) {
      const int i = base + r;
      if (w <= (i >> 6)) {
        const int ip = SK4(i);
        const float x1i = bx1[ip], y1i = by1[ip], x2i = bx2[ip], y2i = by2[ip];
        const float ai = ar[ip];
        unsigned long long mrow = 0ull;
        #pragma unroll
        for (int m4 = 0; m4 < 16; ++m4) {
          const int j0 = (w << 6) + (m4 << 2);
          const int a  = j0 + (w << 2);          // SK4(j0), j0>>6 == w
          float4 X1 = *(const float4*)&bx1[a];
          float4 Y1 = *(const float4*)&by1[a];
          float4 X2 = *(const float4*)&bx2[a];
          float4 Y2 = *(const float4*)&by2[a];
          float4 AR = *(const float4*)&ar[a];
          #define IOU_BIT(JX1,JY1,JX2,JY2,JAR,J)                              \
            { float iw = fminf(x2i,(JX2)) - fmaxf(x1i,(JX1));                 \
              float ih = fminf(y2i,(JY2)) - fmaxf(y1i,(JY1));                 \
              iw = fmaxf(iw,0.f); ih = fmaxf(ih,0.f);                        \
              float inter = iw*ih;                                            \
              float uni = fmaxf(ai + (JAR) - inter, 1e-9f);                   \
              if ((inter/uni > 0.5f) && ((J) < i))                            \
                mrow |= 1ull << ((J) & 63); }
          IOU_BIT(X1.x, Y1.x, X2.x, Y2.x, AR.x, j0 + 0)
          IOU_BIT(X1.y, Y1.y, X2.y, Y2.y, AR.y, j0 + 1)
          IOU_BIT(X1.z, Y1.z, X2.z, Y2.z, AR.z, j0 + 2)
          IOU_BIT(X1.w, Y1.w, X2.w, Y2.w, AR.w, j0 + 3)
          #undef IOU_BIT
        }
        msk[r][w] = mrow;
      } else {
        msk[r][w] = 0ull;
      }
    }
    __syncthreads();

    if (tid < 64) {
      bool stop = false;
      for (int g = 0; g < 16 && !stop; ++g) {
        int r0 = g * 8;
        if (r0 >= rows) break;
        unsigned long long wbuf[8];
        #pragma unroll
        for (int k2 = 0; k2 < 8; ++k2)
          wbuf[k2] = (lane < 8 && (r0 + k2) < rows) ? msk[r0 + k2][lane] : 0ull;
        #pragma unroll
        for (int k2 = 0; k2 < 8; ++k2) {
          if (!stop) {
            int rr = r0 + k2;
            if (rr >= rows) { stop = true; }
            else {
              int i = base + rr;
              bool ov = (Kw & wbuf[k2]) != 0ull;
              if (!__any(ov)) {
                if (lane == (i >> 6)) Kw |= 1ull << (i & 63);
                if (++kept >= MAXPC) stop = true;
              }
            }
          }
        }
      }
      if (lane == 0) svar[5] = (kept >= MAXPC || (base + (rows > 0 ? rows : 0)) >= limit) ? 1u : 0u;
    }
    __syncthreads();
    if (svar[5] != 0u) break;     // block-uniform break
  }

  if (tid < 8) kword[tid] = Kw;   // wave-0 lanes 0..7 hold the kept words
  __syncthreads();

  // ---- write kept entries (prefix over kword)
  if (tid < 512) {
    int rr = tid;
    int wr = rr >> 6;
    unsigned long long kw = kword[wr];
    if ((kw >> (rr & 63)) & 1ull) {
      uint32_t p = 0;
      for (int ww = 0; ww < wr; ++ww) p += (uint32_t)__popcll(kword[ww]);
      p += (uint32_t)__popcll(kw & ((1ull << (rr & 63)) - 1ull));
      selScore[bc * MAXPC + p] = __uint_as_float(skey[rr]);
      selRank[bc * MAXPC + p]  = rr;
      int rp = SK4(rr);
      float* o = &selBox[(size_t)(bc * MAXPC + p) * 4];
      o[0] = bx1[rp]; o[1] = by1[rp]; o[2] = bx2[rp]; o[3] = by2[rp];
    }
  }
  if (tid == 0) {
    uint32_t tot = 0;
    for (int ww = 0; ww < 8; ++ww) tot += (uint32_t)__popcll(kword[ww]);
    selCount[bc] = (int)tot;
  }
}

// ---------------------------------------------------------------- kernel 3
// per image: merge the two class lists (<=200), exact top-100 by
// (score desc, flat index asc) via rank-by-count, write outputs.
__global__ __launch_bounds__(256) void merge_kernel(
    const float* __restrict__ selScore, const float* __restrict__ selBox,
    const int* __restrict__ selRank, const int* __restrict__ selCount,
    float* __restrict__ out)
{
  const int b   = blockIdx.x;
  const int tid = threadIdx.x;
  __shared__ float    es[200];
  __shared__ uint32_t ek[200];
  __shared__ float    eb[200][4];
  const int c0  = selCount[b * 2 + 0];
  const int c1  = selCount[b * 2 + 1];
  const int tot = c0 + c1;                      // <= 200

  if (tid < tot) {
    int cls  = (tid < c0) ? 0 : 1;
    int slot = (cls == 0) ? tid : (tid - c0);
    int src  = (b * 2 + cls) * MAXPC + slot;
    es[tid] = selScore[src];
    ek[tid] = (uint32_t)(cls * KCAND + selRank[src]);   // flat index in (2,512)
    eb[tid][0] = selBox[(size_t)src * 4 + 0];
    eb[tid][1] = selBox[(size_t)src * 4 + 1];
    eb[tid][2] = selBox[(size_t)src * 4 + 2];
    eb[tid][3] = selBox[(size_t)src * 4 + 3];
  }
  __syncthreads();

  float* outBoxes  = out;
  float* outScores = out + (size_t)BATCH * MAXTOT * 4;
  float* outCls    = outScores + (size_t)BATCH * MAXTOT;
  float* outCnt    = outCls + (size_t)BATCH * MAXTOT;
  const int filled = (tot < MAXTOT) ? tot : MAXTOT;

  if (tid < tot) {
    float    s  = es[tid];
    uint32_t fk = ek[tid];
    int rank = 0;
    for (int j = 0; j < tot; j++)
      rank += (int)((es[j] > s) || (es[j] == s && ek[j] < fk));
    if (rank < MAXTOT) {                       // kept: s > 0.5 > 0 always
      outScores[b * MAXTOT + rank] = s;
      outCls[b * MAXTOT + rank]    = (float)(fk >> 9);
      float* ob = &outBoxes[(size_t)(b * MAXTOT + rank) * 4];
      ob[0] = fminf(fmaxf(eb[tid][0], 0.f), 1.f);
      ob[1] = fminf(fmaxf(eb[tid][1], 0.f), 1.f);
      ob[2] = fminf(fmaxf(eb[tid][2], 0.f), 1.f);
      ob[3] = fminf(fmaxf(eb[tid][3], 0.f), 1.f);
    }
  }
  if (tid >= filled && tid < MAXTOT) {         // zero-fill unused slots
    outScores[b * MAXTOT + tid] = 0.f;
    outCls[b * MAXTOT + tid]    = 0.f;
    float* ob = &outBoxes[(size_t)(b * MAXTOT + tid) * 4];
    ob[0] = 0.f; ob[1] = 0.f; ob[2] = 0.f; ob[3] = 0.f;
  }
  if (tid == 0) outCnt[b] = (float)filled;
}

// ---------------------------------------------------------------- launch
extern "C" void kernel_launch(void* const* d_in, const int* in_sizes, int n_in,
                              void* d_out, int out_size, void* d_ws, size_t ws_size,
                              hipStream_t stream)
{
  const float* p1   = (const float*)d_in[0];
  const float* p2   = (const float*)d_in[1];
  const float* p3   = (const float*)d_in[2];
  const float* anch = (const float*)d_in[3];

  uint8_t* ws = (uint8_t*)d_ws;
  uint32_t* counts = (uint32_t*)ws;                                // 2048 u32
  uint2*    cand   = (uint2*)(ws + 16384);                         // 128*16*384*8 = 6 MB
  uint8_t*  wp     = ws + 16384 + (size_t)128 * NSEG * CAPS * 8;
  float*    selScore = (float*)wp;         wp += (size_t)BATCH * 2 * MAXPC * 4;
  float*    selBox   = (float*)wp;         wp += (size_t)BATCH * 2 * MAXPC * 16;
  int*      selRank  = (int*)wp;           wp += (size_t)BATCH * 2 * MAXPC * 4;
  int*      selCount = (int*)wp;

  score_filter_kernel<<<BATCH * NSEG, 256, 0, stream>>>(p1, p2, p3, cand, counts);
  nms_kernel<<<BATCH * 2, 1024, 0, stream>>>(cand, counts, p1, p2, p3, anch,
                                             selScore, selBox, selRank, selCount);
  merge_kernel<<<BATCH, 256, 0, stream>>>(selScore, selBox, selRank, selCount,
                                          (float*)d_out);
}